// Round 1
// baseline (692.044 us; speedup 1.0000x reference)
//
#include <hip/hip_runtime.h>

typedef unsigned int u32;
typedef float f4v __attribute__((ext_vector_type(4)));

#define CG   16
#define HWN  4096
#define LSTR 68

__device__ __forceinline__ float sigm(float x) { return 1.0f / (1.0f + __expf(-x)); }

// __launch_bounds__(512, 6): 6 waves/EU * 4 EU / 8 waves-per-block = 3 blocks/CU.
// LDS trimmed to ~50.2 KB (phase-1 scratch aliased onto s_cb[1]) so 3 blocks fit in 160 KiB.
__global__ __launch_bounds__(512, 6) void ema_kernel(
    const float* __restrict__ x,
    const float* __restrict__ w1, const float* __restrict__ b1,
    const float* __restrict__ w3, const float* __restrict__ b3,
    const float* __restrict__ w5, const float* __restrict__ b5,
    const float* __restrict__ gnw, const float* __restrict__ gnb,
    const float* __restrict__ ew, const float* __restrict__ eb,
    float* __restrict__ out)
{
  __shared__ __align__(16) float s_cb[2][68][LSTR];  // 36992 B channel tile (double buffer)
  // ---- phase-1 scratch ALIASED onto s_cb[1] (dead before buf1's first staging use;
  //      buf1 is re-zeroed in the softmax phase, after the last alias read) ----
  float* const s_row = &s_cb[1][0][0];      // [16][64] flat: c*64+y     (0..1023)
  float* const s_col = s_row + 1024;        // [16][64] flat             (1024..2047)
  float* const s_RS  = s_row + 2048;        // [16][25] flat: c*25+k     (2048..2447)
  float* const s_p2  = s_row + 2448;        // [16][16] flat             (2448..2703)
  float* const s_p3  = s_row + 2704;        // [16][16] flat             (2704..2959) < 4624 OK
  __shared__ __align__(16) float s_sh[16][64];   // sigmoid(x_h2)
  __shared__ __align__(16) float s_sw[16][64];   // sigmoid(x_w2)
  __shared__ __align__(16) float s_W5[16][28];   // effective 5x5 kernel (3x3 folded), padded
  __shared__ float s_ca[16], s_A1[16], s_Cc[16];
  __shared__ float s_w1[256], s_b1[16], s_gnw[16], s_gnb[16], s_b3[16], s_b5[16], s_ecaw[3], s_ecab[1];
  __shared__ float s_m2[16], s_m3[16], s_sm1[16], s_sm2[16], s_sm3[16];
  __shared__ float s_a1[16], s_a2[16], s_a3[16], s_total[16];
  __shared__ float s_red[16][8][2];
  __shared__ float s_scal[2];      // [0]=total constant, [1]=bias_eff

  const int g = blockIdx.x;
  const int t = threadIdx.x;
  const int wv = t >> 6;           // wave 0..7
  const int ln = t & 63;
  const float* px   = x   + (size_t)g * CG * HWN;
  float*       pout = out + (size_t)g * CG * HWN;

  // ---------------- Phase 1: row/col sums; wave w owns channels 2w, 2w+1 ----------------
  {
    const int j4 = ln & 15;        // col group (4 cols)
    const int rr = ln >> 4;        // 0..3 row phase
    #pragma unroll 1
    for (int cc = 0; cc < 2; ++cc) {
      const int c = 2 * wv + cc;
      float rs[16];
      float cp0 = 0.f, cp1 = 0.f, cp2 = 0.f, cp3 = 0.f;
      #pragma unroll
      for (int j = 0; j < 16; ++j) {
        float4 v = *(const float4*)(px + c * HWN + (rr + 4 * j) * 64 + 4 * j4);
        rs[j] = v.x + v.y + v.z + v.w;
        cp0 += v.x; cp1 += v.y; cp2 += v.z; cp3 += v.w;
      }
      #pragma unroll
      for (int j = 0; j < 16; ++j) {
        float r = rs[j];
        r += __shfl_xor(r, 1); r += __shfl_xor(r, 2);
        r += __shfl_xor(r, 4); r += __shfl_xor(r, 8);
        if (j4 == 0) s_row[c * 64 + rr + 4 * j] = r;
      }
      cp0 += __shfl_xor(cp0, 16); cp0 += __shfl_xor(cp0, 32);
      cp1 += __shfl_xor(cp1, 16); cp1 += __shfl_xor(cp1, 32);
      cp2 += __shfl_xor(cp2, 16); cp2 += __shfl_xor(cp2, 32);
      cp3 += __shfl_xor(cp3, 16); cp3 += __shfl_xor(cp3, 32);
      if (rr == 0) *(float4*)&s_col[c * 64 + 4 * j4] = make_float4(cp0, cp1, cp2, cp3);
    }
  }
  // small weight vectors -> LDS
  if (t < 256) s_w1[t] = w1[t];
  if (t < 16) {
    s_b1[t]  = b1[t];  s_gnw[t] = gnw[t]; s_gnb[t] = gnb[t];
    s_b3[t]  = b3[t];  s_b5[t]  = b5[t];
  }
  if (t < 3)  s_ecaw[t] = ew[t];
  if (t == 0) s_ecab[0] = eb[0];
  __syncthreads();

  if (t < 16) { float s = 0.f; for (int y = 0; y < 64; ++y) s += s_row[t * 64 + y]; s_total[t] = s; }
  __syncthreads();

  // ---------------- conv1x1 (+sigmoid), zero buf0 (only!), 5x5 region sums ----------------
  #pragma unroll
  for (int m = 0; m < 4; ++m) {
    int idx = t + 512 * m; int o = idx >> 7, pos = idx & 127;
    float acc = s_b1[o];
    const float inv64 = 1.0f / 64.0f;
    #pragma unroll
    for (int i = 0; i < 16; ++i) {
      float v = (pos < 64 ? s_row[i * 64 + pos] : s_col[i * 64 + pos - 64]) * inv64;
      acc += s_w1[o * 16 + i] * v;
    }
    float sg = sigm(acc);
    if (pos < 64) s_sh[o][pos] = sg; else s_sw[o][pos - 64] = sg;
  }
  // zero buffer 0 only (buffer 1 still holds the aliased scratch)
  #pragma unroll
  for (int m = 0; m < 3; ++m) { int idx = t + 512 * m; if (idx < 1156) ((float4*)&s_cb[0][0][0])[idx] = make_float4(0.f, 0.f, 0.f, 0.f); }
  if (t < 400) {
    int i = t / 25, kk = t % 25;
    int dy = kk / 5 - 2, dx = kk % 5 - 2;
    int a  = dy > 0 ? dy : 0,   b  = 64 + (dy < 0 ? dy : 0);
    int cl = dx > 0 ? dx : 0,   d  = 64 + (dx < 0 ? dx : 0);
    float S = s_total[i];
    if (a > 0)  S -= s_row[i * 64 + 0];
    if (a > 1)  S -= s_row[i * 64 + 1];
    if (b < 64) S -= s_row[i * 64 + 63];
    if (b < 63) S -= s_row[i * 64 + 62];
    for (int x0 = 0; x0 < cl; ++x0) {
      float cv = s_col[i * 64 + x0];
      if (a > 0)  cv -= px[i * HWN + 0 * 64  + x0];
      if (a > 1)  cv -= px[i * HWN + 1 * 64  + x0];
      if (b < 64) cv -= px[i * HWN + 63 * 64 + x0];
      if (b < 63) cv -= px[i * HWN + 62 * 64 + x0];
      S -= cv;
    }
    for (int x0 = d; x0 < 64; ++x0) {
      float cv = s_col[i * 64 + x0];
      if (a > 0)  cv -= px[i * HWN + 0 * 64  + x0];
      if (a > 1)  cv -= px[i * HWN + 1 * 64  + x0];
      if (b < 64) cv -= px[i * HWN + 63 * 64 + x0];
      if (b < 63) cv -= px[i * HWN + 62 * 64 + x0];
      S -= cv;
    }
    s_RS[i * 25 + kk] = S;
  }
  __syncthreads();

  // ---------------- mean(x2), mean(x3) via region sums ----------------
  if (t < 256) {
    int o = t >> 4, i = t & 15;
    float p2 = 0.f, p3 = 0.f;
    const float* w3b = w3 + (o * 16 + i) * 9;
    const float* w5b = w5 + (o * 16 + i) * 25;
    #pragma unroll
    for (int ky = 0; ky < 3; ++ky)
      #pragma unroll
      for (int kx = 0; kx < 3; ++kx)
        p2 += w3b[ky * 3 + kx] * s_RS[i * 25 + (ky + 1) * 5 + (kx + 1)];
    #pragma unroll
    for (int kk = 0; kk < 25; ++kk) p3 += w5b[kk] * s_RS[i * 25 + kk];
    s_p2[o * 16 + i] = p2; s_p3[o * 16 + i] = p3;
  }
  __syncthreads();
  if (t < 16)      { float s = 0.f; for (int i = 0; i < 16; ++i) s += s_p2[t * 16 + i];        s_m2[t] = s_b3[t] + s * (1.0f/4096.0f); }
  else if (t < 32) { int o = t - 16; float s = 0.f; for (int i = 0; i < 16; ++i) s += s_p3[o * 16 + i]; s_m3[o] = s_b5[o] + s * (1.0f/4096.0f); }
  __syncthreads();

  // ---------------- softmaxes over channel means (mean(x1) == gn_b exactly) ----------------
  // All aliased scratch (s_row/s_col/s_RS/s_p2/s_p3) is now dead: zero buffer 1 here.
  #pragma unroll
  for (int m = 0; m < 3; ++m) { int idx = t + 512 * m; if (idx < 1156) ((float4*)&s_cb[1][0][0])[idx] = make_float4(0.f, 0.f, 0.f, 0.f); }
  if (t < 3) {
    const float* m = (t == 0) ? s_gnb : (t == 1) ? s_m2 : s_m3;
    float* dst     = (t == 0) ? s_sm1 : (t == 1) ? s_sm2 : s_sm3;
    float mx = m[0];
    for (int c = 1; c < 16; ++c) mx = fmaxf(mx, m[c]);
    float e[16], ssum = 0.f;
    for (int c = 0; c < 16; ++c) { e[c] = __expf(m[c] - mx); ssum += e[c]; }
    float r = 1.0f / ssum;
    for (int c = 0; c < 16; ++c) dst[c] = e[c] * r;
  }
  __syncthreads();

  // ---------------- ECA (-> ca) and mixing coefficients ----------------
  if (t < 16) {
    int c = t;
    float casum = 0.f;
    #pragma unroll
    for (int v = 0; v < 3; ++v) {
      const float* m = (v == 0) ? s_gnb : (v == 1) ? s_m2 : s_m3;
      float acc = s_ecab[0] + s_ecaw[1] * m[c];
      if (c > 0)  acc += s_ecaw[0] * m[c - 1];
      if (c < 15) acc += s_ecaw[2] * m[c + 1];
      casum += sigm(acc);
    }
    s_ca[c] = casum;
    s_a1[c] = s_sm2[c] + s_sm3[c];
    s_a2[c] = s_sm1[c] + s_sm3[c];
    s_a3[c] = s_sm1[c] + s_sm2[c];
  }
  __syncthreads();

  // ---------------- effective 5x5 kernel (3x3 folded) + bias; prefetch ch0 stage ----------------
  // T14 async-STAGE split: LOAD issues global reads to regs; WRITE commits to LDS later,
  // so the vmcnt wait lands after the conv compute instead of before it.
  #define STAGE_LOAD(c, ra, rb) {                                        \
    const float* sp = px + (size_t)(c) * HWN + (t >> 4) * 64 + (t & 15) * 4; \
    ra = *(const float4*)sp;                                             \
    rb = *(const float4*)(sp + 2048);                                    \
  }
  #define STAGE_WRITE(buf, ra, rb) {                                     \
    float* d0 = &s_cb[buf][2 + (t >> 4)][2 + (t & 15) * 4];              \
    *(float2*)d0       = make_float2(ra.x, ra.y);                        \
    *(float2*)(d0 + 2) = make_float2(ra.z, ra.w);                        \
    float* d1 = d0 + 32 * LSTR;                                          \
    *(float2*)d1       = make_float2(rb.x, rb.y);                        \
    *(float2*)(d1 + 2) = make_float2(rb.z, rb.w);                        \
  }

  if (t == 0) {
    float s = 0.f;
    for (int o = 0; o < 16; ++o) s += s_a2[o] * s_b3[o] + s_a3[o] * s_b5[o];
    s_scal[1] = s;
  }
  if (t < 448) {
    if (t < 400) {
      int i = t / 25, kk = t % 25, ky = kk / 5, kx = kk % 5;
      float acc = 0.f;
      #pragma unroll
      for (int o = 0; o < 16; ++o) acc += s_a3[o] * w5[((o * 16 + i) * 5 + ky) * 5 + kx];
      if (ky >= 1 && ky <= 3 && kx >= 1 && kx <= 3) {
        #pragma unroll
        for (int o = 0; o < 16; ++o) acc += s_a2[o] * w3[((o * 16 + i) * 3 + (ky - 1)) * 3 + (kx - 1)];
      }
      s_W5[i][kk] = acc;
    } else {
      int q = t - 400; s_W5[q / 3][25 + q % 3] = 0.f;
    }
  }
  {
    float4 p0, p1;
    STAGE_LOAD(0, p0, p1);
    STAGE_WRITE(0, p0, p1);
  }
  __syncthreads();

  // ---------------- Conv sweep: 2x4 tile/thread, pipelined GN->A1->gated fold ----------------
  const int x0 = 4 * (t & 15);
  const int y0 = 2 * (t >> 4);     // 0..62

  float ws[8];
  #pragma unroll
  for (int i = 0; i < 8; ++i) ws[i] = 0.f;
  float gsv[2][8];
  float4 st0, st1;

  #pragma unroll 1
  for (int c = 0; c < 16; ++c) {
    if (c < 15) STAGE_LOAD(c + 1, st0, st1);   // issue early: latency hides under conv
    // finalize GN stats of channel c-1 (s_red written in iter c-1, visible after barrier)
    if (c >= 1 && t == 0) {
      float S = 0.f, Q = 0.f;
      #pragma unroll
      for (int w = 0; w < 8; ++w) { S += s_red[c-1][w][0]; Q += s_red[c-1][w][1]; }
      float mu  = S * (1.0f / 4096.0f);
      float var = Q * (1.0f / 4096.0f) - mu * mu;
      float inv = rsqrtf(var + 1e-5f);
      s_A1[c-1] = s_a1[c-1] * s_gnw[c-1] * inv;
      s_Cc[c-1] = s_a1[c-1] * (s_gnb[c-1] - mu * s_gnw[c-1] * inv);
    }
    // fold gated term of channel c-2 (A1[c-2] finalized in iter c-1, barrier since)
    if (c >= 2) {
      float a1v = s_A1[c-2];
      #pragma unroll
      for (int i = 0; i < 8; ++i) ws[i] += a1v * gsv[c & 1][i];
    }
    float Wk[28];
    #pragma unroll
    for (int i = 0; i < 7; ++i) *(float4*)&Wk[4 * i] = *(float4*)&s_W5[c][4 * i];
    float shv0 = s_sh[c][y0], shv1 = s_sh[c][y0 + 1];
    float swv[4];
    #pragma unroll
    for (int r = 0; r < 4; ++r) swv[r] = s_sw[c][x0 + r];
    const float* base = &s_cb[c & 1][0][0] + y0 * LSTR + x0;
    float gsl = 0.f, gql = 0.f;
    #pragma unroll
    for (int q = 0; q < 6; ++q) {
      const float* rp = base + q * LSTR;
      float4 A = *(const float4*)rp, B = *(const float4*)(rp + 4);
      float v[8] = {A.x, A.y, A.z, A.w, B.x, B.y, B.z, B.w};
      if (q == 2 || q == 3) {          // center rows: GN stats + save gated values
        const float sh_ = (q == 2) ? shv0 : shv1;
        const int ri = q - 2;
        #pragma unroll
        for (int m = 0; m < 4; ++m) {
          float gg = v[m + 2] * sh_ * swv[m];
          gsl += gg; gql += gg * gg;
          gsv[c & 1][4 * ri + m] = gg;
        }
      }
      #pragma unroll
      for (int r = 0; r < 2; ++r) {
        const int kr = q - r;
        if (kr >= 0 && kr <= 4) {
          #pragma unroll
          for (int m = 0; m < 4; ++m) {
            float a = ws[4 * r + m];
            a += Wk[kr * 5 + 0] * v[m + 0];
            a += Wk[kr * 5 + 1] * v[m + 1];
            a += Wk[kr * 5 + 2] * v[m + 2];
            a += Wk[kr * 5 + 3] * v[m + 3];
            a += Wk[kr * 5 + 4] * v[m + 4];
            ws[4 * r + m] = a;
          }
        }
      }
    }
    if (c < 15) STAGE_WRITE((c + 1) & 1, st0, st1);   // commit: loads have landed by now
    gsl += __shfl_xor(gsl, 1);  gql += __shfl_xor(gql, 1);
    gsl += __shfl_xor(gsl, 2);  gql += __shfl_xor(gql, 2);
    gsl += __shfl_xor(gsl, 4);  gql += __shfl_xor(gql, 4);
    gsl += __shfl_xor(gsl, 8);  gql += __shfl_xor(gql, 8);
    gsl += __shfl_xor(gsl, 16); gql += __shfl_xor(gql, 16);
    gsl += __shfl_xor(gsl, 32); gql += __shfl_xor(gql, 32);
    if (ln == 0) { s_red[c][wv][0] = gsl; s_red[c][wv][1] = gql; }
    __syncthreads();
  }

  // ---------------- tail: finalize ch15, total constant, fold ch14/ch15 ----------------
  if (t == 0) {
    float S = 0.f, Q = 0.f;
    #pragma unroll
    for (int w = 0; w < 8; ++w) { S += s_red[15][w][0]; Q += s_red[15][w][1]; }
    float mu  = S * (1.0f / 4096.0f);
    float var = Q * (1.0f / 4096.0f) - mu * mu;
    float inv = rsqrtf(var + 1e-5f);
    s_A1[15] = s_a1[15] * s_gnw[15] * inv;
    s_Cc[15] = s_a1[15] * (s_gnb[15] - mu * s_gnw[15] * inv);
    float s = s_scal[1];
    for (int c = 0; c < 16; ++c) s += s_Cc[c];
    s_scal[0] = s;
  }
  __syncthreads();
  {
    const float a14 = s_A1[14], a15 = s_A1[15], Ct = s_scal[0];
    #pragma unroll
    for (int i = 0; i < 8; ++i)
      ws[i] = sigm(ws[i] + a14 * gsv[0][i] + a15 * gsv[1][i] + Ct);
  }

  // ---------------- Epilogue: out = X * ca[c] * sigmoid(weights) ----------------
  // Nontemporal stores: keep the LLC-resident copy of x (re-read 2x) from being
  // thrashed by the 134 MB output stream.
  #pragma unroll
  for (int c = 0; c < 16; ++c) {
    const float cav = s_ca[c];
    const float* xp = px   + c * HWN + y0 * 64 + x0;
    float*       op = pout + c * HWN + y0 * 64 + x0;
    float4 xa = *(const float4*)xp;
    float4 xb = *(const float4*)(xp + 64);
    float4 oa, ob;
    oa.x = xa.x * cav * ws[0]; oa.y = xa.y * cav * ws[1];
    oa.z = xa.z * cav * ws[2]; oa.w = xa.w * cav * ws[3];
    ob.x = xb.x * cav * ws[4]; ob.y = xb.y * cav * ws[5];
    ob.z = xb.z * cav * ws[6]; ob.w = xb.w * cav * ws[7];
    __builtin_nontemporal_store(*(f4v*)&oa, (f4v*)op);
    __builtin_nontemporal_store(*(f4v*)&ob, (f4v*)(op + 64));
  }
}

extern "C" void kernel_launch(void* const* d_in, const int* in_sizes, int n_in,
                              void* d_out, int out_size, void* d_ws, size_t ws_size,
                              hipStream_t stream) {
  const float* X  = (const float*)d_in[0];
  const float* W1 = (const float*)d_in[1];
  const float* B1 = (const float*)d_in[2];
  const float* W3 = (const float*)d_in[3];
  const float* B3 = (const float*)d_in[4];
  const float* W5 = (const float*)d_in[5];
  const float* B5 = (const float*)d_in[6];
  const float* GW = (const float*)d_in[7];
  const float* GB = (const float*)d_in[8];
  const float* EW = (const float*)d_in[9];
  const float* EB = (const float*)d_in[10];
  float* O = (float*)d_out;
  ema_kernel<<<dim3(512), dim3(512), 0, stream>>>(X, W1, B1, W3, B3, W5, B5, GW, GB, EW, EB, O);
}

// Round 2
// 393.323 us; speedup vs baseline: 1.7595x; 1.7595x over previous
//
#include <hip/hip_runtime.h>

typedef unsigned int u32;
typedef float f4v __attribute__((ext_vector_type(4)));

#define CG   16
#define HWN  4096
#define LSTR 68

__device__ __forceinline__ float sigm(float x) { return 1.0f / (1.0f + __expf(-x)); }

// __launch_bounds__(512, 4): known-good bound (no forced register cap / no spills).
// LDS is 50,176 B, so if the natural VGPR allocation lands <=85 the HW gives
// 6 waves/EU = 3 blocks/CU on its own; if not, we keep the baseline's 2 blocks/CU.
__global__ __launch_bounds__(512, 4) void ema_kernel(
    const float* __restrict__ x,
    const float* __restrict__ w1, const float* __restrict__ b1,
    const float* __restrict__ w3, const float* __restrict__ b3,
    const float* __restrict__ w5, const float* __restrict__ b5,
    const float* __restrict__ gnw, const float* __restrict__ gnb,
    const float* __restrict__ ew, const float* __restrict__ eb,
    float* __restrict__ out)
{
  __shared__ __align__(16) float s_cb[2][68][LSTR];  // 36992 B channel tile (double buffer)
  // ---- phase-1 scratch ALIASED onto s_cb[1] (dead before buf1's first staging use;
  //      buf1 is re-zeroed in the softmax phase, after the last alias read) ----
  float* const s_row = &s_cb[1][0][0];      // [16][64] flat: c*64+y     (0..1023)
  float* const s_col = s_row + 1024;        // [16][64] flat             (1024..2047)
  float* const s_RS  = s_row + 2048;        // [16][25] flat: c*25+k     (2048..2447)
  float* const s_p2  = s_row + 2448;        // [16][16] flat             (2448..2703)
  float* const s_p3  = s_row + 2704;        // [16][16] flat             (2704..2959) < 4624 OK
  __shared__ __align__(16) float s_sh[16][64];   // sigmoid(x_h2)
  __shared__ __align__(16) float s_sw[16][64];   // sigmoid(x_w2)
  __shared__ __align__(16) float s_W5[16][28];   // effective 5x5 kernel (3x3 folded), padded
  __shared__ float s_ca[16], s_A1[16], s_Cc[16];
  __shared__ float s_w1[256], s_b1[16], s_gnw[16], s_gnb[16], s_b3[16], s_b5[16], s_ecaw[3], s_ecab[1];
  __shared__ float s_m2[16], s_m3[16], s_sm1[16], s_sm2[16], s_sm3[16];
  __shared__ float s_a1[16], s_a2[16], s_a3[16], s_total[16];
  __shared__ float s_red[16][8][2];
  __shared__ float s_scal[2];      // [0]=total constant, [1]=bias_eff

  const int g = blockIdx.x;
  const int t = threadIdx.x;
  const int wv = t >> 6;           // wave 0..7
  const int ln = t & 63;
  const float* px   = x   + (size_t)g * CG * HWN;
  float*       pout = out + (size_t)g * CG * HWN;

  // ---------------- Phase 1: row/col sums; wave w owns channels 2w, 2w+1 ----------------
  {
    const int j4 = ln & 15;        // col group (4 cols)
    const int rr = ln >> 4;        // 0..3 row phase
    #pragma unroll 1
    for (int cc = 0; cc < 2; ++cc) {
      const int c = 2 * wv + cc;
      float rs[16];
      float cp0 = 0.f, cp1 = 0.f, cp2 = 0.f, cp3 = 0.f;
      #pragma unroll
      for (int j = 0; j < 16; ++j) {
        float4 v = *(const float4*)(px + c * HWN + (rr + 4 * j) * 64 + 4 * j4);
        rs[j] = v.x + v.y + v.z + v.w;
        cp0 += v.x; cp1 += v.y; cp2 += v.z; cp3 += v.w;
      }
      #pragma unroll
      for (int j = 0; j < 16; ++j) {
        float r = rs[j];
        r += __shfl_xor(r, 1); r += __shfl_xor(r, 2);
        r += __shfl_xor(r, 4); r += __shfl_xor(r, 8);
        if (j4 == 0) s_row[c * 64 + rr + 4 * j] = r;
      }
      cp0 += __shfl_xor(cp0, 16); cp0 += __shfl_xor(cp0, 32);
      cp1 += __shfl_xor(cp1, 16); cp1 += __shfl_xor(cp1, 32);
      cp2 += __shfl_xor(cp2, 16); cp2 += __shfl_xor(cp2, 32);
      cp3 += __shfl_xor(cp3, 16); cp3 += __shfl_xor(cp3, 32);
      if (rr == 0) *(float4*)&s_col[c * 64 + 4 * j4] = make_float4(cp0, cp1, cp2, cp3);
    }
  }
  // small weight vectors -> LDS
  if (t < 256) s_w1[t] = w1[t];
  if (t < 16) {
    s_b1[t]  = b1[t];  s_gnw[t] = gnw[t]; s_gnb[t] = gnb[t];
    s_b3[t]  = b3[t];  s_b5[t]  = b5[t];
  }
  if (t < 3)  s_ecaw[t] = ew[t];
  if (t == 0) s_ecab[0] = eb[0];
  __syncthreads();

  if (t < 16) { float s = 0.f; for (int y = 0; y < 64; ++y) s += s_row[t * 64 + y]; s_total[t] = s; }
  __syncthreads();

  // ---------------- conv1x1 (+sigmoid), zero buf0 (only!), 5x5 region sums ----------------
  #pragma unroll
  for (int m = 0; m < 4; ++m) {
    int idx = t + 512 * m; int o = idx >> 7, pos = idx & 127;
    float acc = s_b1[o];
    const float inv64 = 1.0f / 64.0f;
    #pragma unroll
    for (int i = 0; i < 16; ++i) {
      float v = (pos < 64 ? s_row[i * 64 + pos] : s_col[i * 64 + pos - 64]) * inv64;
      acc += s_w1[o * 16 + i] * v;
    }
    float sg = sigm(acc);
    if (pos < 64) s_sh[o][pos] = sg; else s_sw[o][pos - 64] = sg;
  }
  // zero buffer 0 only (buffer 1 still holds the aliased scratch)
  #pragma unroll
  for (int m = 0; m < 3; ++m) { int idx = t + 512 * m; if (idx < 1156) ((float4*)&s_cb[0][0][0])[idx] = make_float4(0.f, 0.f, 0.f, 0.f); }
  if (t < 400) {
    int i = t / 25, kk = t % 25;
    int dy = kk / 5 - 2, dx = kk % 5 - 2;
    int a  = dy > 0 ? dy : 0,   b  = 64 + (dy < 0 ? dy : 0);
    int cl = dx > 0 ? dx : 0,   d  = 64 + (dx < 0 ? dx : 0);
    float S = s_total[i];
    if (a > 0)  S -= s_row[i * 64 + 0];
    if (a > 1)  S -= s_row[i * 64 + 1];
    if (b < 64) S -= s_row[i * 64 + 63];
    if (b < 63) S -= s_row[i * 64 + 62];
    for (int x0 = 0; x0 < cl; ++x0) {
      float cv = s_col[i * 64 + x0];
      if (a > 0)  cv -= px[i * HWN + 0 * 64  + x0];
      if (a > 1)  cv -= px[i * HWN + 1 * 64  + x0];
      if (b < 64) cv -= px[i * HWN + 63 * 64 + x0];
      if (b < 63) cv -= px[i * HWN + 62 * 64 + x0];
      S -= cv;
    }
    for (int x0 = d; x0 < 64; ++x0) {
      float cv = s_col[i * 64 + x0];
      if (a > 0)  cv -= px[i * HWN + 0 * 64  + x0];
      if (a > 1)  cv -= px[i * HWN + 1 * 64  + x0];
      if (b < 64) cv -= px[i * HWN + 63 * 64 + x0];
      if (b < 63) cv -= px[i * HWN + 62 * 64 + x0];
      S -= cv;
    }
    s_RS[i * 25 + kk] = S;
  }
  __syncthreads();

  // ---------------- mean(x2), mean(x3) via region sums ----------------
  if (t < 256) {
    int o = t >> 4, i = t & 15;
    float p2 = 0.f, p3 = 0.f;
    const float* w3b = w3 + (o * 16 + i) * 9;
    const float* w5b = w5 + (o * 16 + i) * 25;
    #pragma unroll
    for (int ky = 0; ky < 3; ++ky)
      #pragma unroll
      for (int kx = 0; kx < 3; ++kx)
        p2 += w3b[ky * 3 + kx] * s_RS[i * 25 + (ky + 1) * 5 + (kx + 1)];
    #pragma unroll
    for (int kk = 0; kk < 25; ++kk) p3 += w5b[kk] * s_RS[i * 25 + kk];
    s_p2[o * 16 + i] = p2; s_p3[o * 16 + i] = p3;
  }
  __syncthreads();
  if (t < 16)      { float s = 0.f; for (int i = 0; i < 16; ++i) s += s_p2[t * 16 + i];        s_m2[t] = s_b3[t] + s * (1.0f/4096.0f); }
  else if (t < 32) { int o = t - 16; float s = 0.f; for (int i = 0; i < 16; ++i) s += s_p3[o * 16 + i]; s_m3[o] = s_b5[o] + s * (1.0f/4096.0f); }
  __syncthreads();

  // ---------------- softmaxes over channel means (mean(x1) == gn_b exactly) ----------------
  // All aliased scratch (s_row/s_col/s_RS/s_p2/s_p3) is now dead: zero buffer 1 here.
  #pragma unroll
  for (int m = 0; m < 3; ++m) { int idx = t + 512 * m; if (idx < 1156) ((float4*)&s_cb[1][0][0])[idx] = make_float4(0.f, 0.f, 0.f, 0.f); }
  if (t < 3) {
    const float* m = (t == 0) ? s_gnb : (t == 1) ? s_m2 : s_m3;
    float* dst     = (t == 0) ? s_sm1 : (t == 1) ? s_sm2 : s_sm3;
    float mx = m[0];
    for (int c = 1; c < 16; ++c) mx = fmaxf(mx, m[c]);
    float e[16], ssum = 0.f;
    for (int c = 0; c < 16; ++c) { e[c] = __expf(m[c] - mx); ssum += e[c]; }
    float r = 1.0f / ssum;
    for (int c = 0; c < 16; ++c) dst[c] = e[c] * r;
  }
  __syncthreads();

  // ---------------- ECA (-> ca) and mixing coefficients ----------------
  if (t < 16) {
    int c = t;
    float casum = 0.f;
    #pragma unroll
    for (int v = 0; v < 3; ++v) {
      const float* m = (v == 0) ? s_gnb : (v == 1) ? s_m2 : s_m3;
      float acc = s_ecab[0] + s_ecaw[1] * m[c];
      if (c > 0)  acc += s_ecaw[0] * m[c - 1];
      if (c < 15) acc += s_ecaw[2] * m[c + 1];
      casum += sigm(acc);
    }
    s_ca[c] = casum;
    s_a1[c] = s_sm2[c] + s_sm3[c];
    s_a2[c] = s_sm1[c] + s_sm3[c];
    s_a3[c] = s_sm1[c] + s_sm2[c];
  }
  __syncthreads();

  // ---------------- effective 5x5 kernel (3x3 folded) + bias; prefetch ch0 stage ----------------
  // T14 async-STAGE split: LOAD issues global reads to regs; WRITE commits to LDS later,
  // so the vmcnt wait lands after the conv compute instead of before it.
  #define STAGE_LOAD(c, ra, rb) {                                        \
    const float* sp = px + (size_t)(c) * HWN + (t >> 4) * 64 + (t & 15) * 4; \
    ra = *(const float4*)sp;                                             \
    rb = *(const float4*)(sp + 2048);                                    \
  }
  #define STAGE_WRITE(buf, ra, rb) {                                     \
    float* d0 = &s_cb[buf][2 + (t >> 4)][2 + (t & 15) * 4];              \
    *(float2*)d0       = make_float2(ra.x, ra.y);                        \
    *(float2*)(d0 + 2) = make_float2(ra.z, ra.w);                        \
    float* d1 = d0 + 32 * LSTR;                                          \
    *(float2*)d1       = make_float2(rb.x, rb.y);                        \
    *(float2*)(d1 + 2) = make_float2(rb.z, rb.w);                        \
  }

  if (t == 0) {
    float s = 0.f;
    for (int o = 0; o < 16; ++o) s += s_a2[o] * s_b3[o] + s_a3[o] * s_b5[o];
    s_scal[1] = s;
  }
  if (t < 448) {
    if (t < 400) {
      int i = t / 25, kk = t % 25, ky = kk / 5, kx = kk % 5;
      float acc = 0.f;
      #pragma unroll
      for (int o = 0; o < 16; ++o) acc += s_a3[o] * w5[((o * 16 + i) * 5 + ky) * 5 + kx];
      if (ky >= 1 && ky <= 3 && kx >= 1 && kx <= 3) {
        #pragma unroll
        for (int o = 0; o < 16; ++o) acc += s_a2[o] * w3[((o * 16 + i) * 3 + (ky - 1)) * 3 + (kx - 1)];
      }
      s_W5[i][kk] = acc;
    } else {
      int q = t - 400; s_W5[q / 3][25 + q % 3] = 0.f;
    }
  }
  {
    float4 p0, p1;
    STAGE_LOAD(0, p0, p1);
    STAGE_WRITE(0, p0, p1);
  }
  __syncthreads();

  // ---------------- Conv sweep: 2x4 tile/thread, pipelined GN->A1->gated fold ----------------
  const int x0 = 4 * (t & 15);
  const int y0 = 2 * (t >> 4);     // 0..62

  float ws[8];
  #pragma unroll
  for (int i = 0; i < 8; ++i) ws[i] = 0.f;
  float gsv[2][8];
  float4 st0, st1;

  #pragma unroll 1
  for (int c = 0; c < 16; ++c) {
    if (c < 15) STAGE_LOAD(c + 1, st0, st1);   // issue early: latency hides under conv
    // finalize GN stats of channel c-1 (s_red written in iter c-1, visible after barrier)
    if (c >= 1 && t == 0) {
      float S = 0.f, Q = 0.f;
      #pragma unroll
      for (int w = 0; w < 8; ++w) { S += s_red[c-1][w][0]; Q += s_red[c-1][w][1]; }
      float mu  = S * (1.0f / 4096.0f);
      float var = Q * (1.0f / 4096.0f) - mu * mu;
      float inv = rsqrtf(var + 1e-5f);
      s_A1[c-1] = s_a1[c-1] * s_gnw[c-1] * inv;
      s_Cc[c-1] = s_a1[c-1] * (s_gnb[c-1] - mu * s_gnw[c-1] * inv);
    }
    // fold gated term of channel c-2 (A1[c-2] finalized in iter c-1, barrier since)
    if (c >= 2) {
      float a1v = s_A1[c-2];
      #pragma unroll
      for (int i = 0; i < 8; ++i) ws[i] += a1v * gsv[c & 1][i];
    }
    float Wk[28];
    #pragma unroll
    for (int i = 0; i < 7; ++i) *(float4*)&Wk[4 * i] = *(float4*)&s_W5[c][4 * i];
    float shv0 = s_sh[c][y0], shv1 = s_sh[c][y0 + 1];
    float swv[4];
    #pragma unroll
    for (int r = 0; r < 4; ++r) swv[r] = s_sw[c][x0 + r];
    const float* base = &s_cb[c & 1][0][0] + y0 * LSTR + x0;
    float gsl = 0.f, gql = 0.f;
    #pragma unroll
    for (int q = 0; q < 6; ++q) {
      const float* rp = base + q * LSTR;
      float4 A = *(const float4*)rp, B = *(const float4*)(rp + 4);
      float v[8] = {A.x, A.y, A.z, A.w, B.x, B.y, B.z, B.w};
      if (q == 2 || q == 3) {          // center rows: GN stats + save gated values
        const float sh_ = (q == 2) ? shv0 : shv1;
        const int ri = q - 2;
        #pragma unroll
        for (int m = 0; m < 4; ++m) {
          float gg = v[m + 2] * sh_ * swv[m];
          gsl += gg; gql += gg * gg;
          gsv[c & 1][4 * ri + m] = gg;
        }
      }
      #pragma unroll
      for (int r = 0; r < 2; ++r) {
        const int kr = q - r;
        if (kr >= 0 && kr <= 4) {
          #pragma unroll
          for (int m = 0; m < 4; ++m) {
            float a = ws[4 * r + m];
            a += Wk[kr * 5 + 0] * v[m + 0];
            a += Wk[kr * 5 + 1] * v[m + 1];
            a += Wk[kr * 5 + 2] * v[m + 2];
            a += Wk[kr * 5 + 3] * v[m + 3];
            a += Wk[kr * 5 + 4] * v[m + 4];
            ws[4 * r + m] = a;
          }
        }
      }
    }
    if (c < 15) STAGE_WRITE((c + 1) & 1, st0, st1);   // commit: loads have landed by now
    gsl += __shfl_xor(gsl, 1);  gql += __shfl_xor(gql, 1);
    gsl += __shfl_xor(gsl, 2);  gql += __shfl_xor(gql, 2);
    gsl += __shfl_xor(gsl, 4);  gql += __shfl_xor(gql, 4);
    gsl += __shfl_xor(gsl, 8);  gql += __shfl_xor(gql, 8);
    gsl += __shfl_xor(gsl, 16); gql += __shfl_xor(gql, 16);
    gsl += __shfl_xor(gsl, 32); gql += __shfl_xor(gql, 32);
    if (ln == 0) { s_red[c][wv][0] = gsl; s_red[c][wv][1] = gql; }
    __syncthreads();
  }

  // ---------------- tail: finalize ch15, total constant, fold ch14/ch15 ----------------
  if (t == 0) {
    float S = 0.f, Q = 0.f;
    #pragma unroll
    for (int w = 0; w < 8; ++w) { S += s_red[15][w][0]; Q += s_red[15][w][1]; }
    float mu  = S * (1.0f / 4096.0f);
    float var = Q * (1.0f / 4096.0f) - mu * mu;
    float inv = rsqrtf(var + 1e-5f);
    s_A1[15] = s_a1[15] * s_gnw[15] * inv;
    s_Cc[15] = s_a1[15] * (s_gnb[15] - mu * s_gnw[15] * inv);
    float s = s_scal[1];
    for (int c = 0; c < 16; ++c) s += s_Cc[c];
    s_scal[0] = s;
  }
  __syncthreads();
  {
    const float a14 = s_A1[14], a15 = s_A1[15], Ct = s_scal[0];
    #pragma unroll
    for (int i = 0; i < 8; ++i)
      ws[i] = sigm(ws[i] + a14 * gsv[0][i] + a15 * gsv[1][i] + Ct);
  }

  // ---------------- Epilogue: out = X * ca[c] * sigmoid(weights) ----------------
  // Nontemporal stores: keep the LLC-resident copy of x (re-read 2x) from being
  // thrashed by the 134 MB output stream.
  #pragma unroll
  for (int c = 0; c < 16; ++c) {
    const float cav = s_ca[c];
    const float* xp = px   + c * HWN + y0 * 64 + x0;
    float*       op = pout + c * HWN + y0 * 64 + x0;
    float4 xa = *(const float4*)xp;
    float4 xb = *(const float4*)(xp + 64);
    float4 oa, ob;
    oa.x = xa.x * cav * ws[0]; oa.y = xa.y * cav * ws[1];
    oa.z = xa.z * cav * ws[2]; oa.w = xa.w * cav * ws[3];
    ob.x = xb.x * cav * ws[4]; ob.y = xb.y * cav * ws[5];
    ob.z = xb.z * cav * ws[6]; ob.w = xb.w * cav * ws[7];
    __builtin_nontemporal_store(*(f4v*)&oa, (f4v*)op);
    __builtin_nontemporal_store(*(f4v*)&ob, (f4v*)(op + 64));
  }
}

extern "C" void kernel_launch(void* const* d_in, const int* in_sizes, int n_in,
                              void* d_out, int out_size, void* d_ws, size_t ws_size,
                              hipStream_t stream) {
  const float* X  = (const float*)d_in[0];
  const float* W1 = (const float*)d_in[1];
  const float* B1 = (const float*)d_in[2];
  const float* W3 = (const float*)d_in[3];
  const float* B3 = (const float*)d_in[4];
  const float* W5 = (const float*)d_in[5];
  const float* B5 = (const float*)d_in[6];
  const float* GW = (const float*)d_in[7];
  const float* GB = (const float*)d_in[8];
  const float* EW = (const float*)d_in[9];
  const float* EB = (const float*)d_in[10];
  float* O = (float*)d_out;
  ema_kernel<<<dim3(512), dim3(512), 0, stream>>>(X, W1, B1, W3, B3, W5, B5, GW, GB, EW, EB, O);
}

// Round 3
// 345.037 us; speedup vs baseline: 2.0057x; 1.1399x over previous
//
#include <hip/hip_runtime.h>

#define CG   16
#define HWN  4096
#define LSTR 68
#define PSTRIDE 2560   // floats per group: sh 1024 | sw 1024 | W5 448 | A1 16 | ca 16 | Ct 1

// Static device param buffer (5.24 MB) — avoids any d_ws size assumption,
// graph-capture safe (no hipMalloc).
__device__ float g_params[512 * PSTRIDE];

__device__ __forceinline__ float sigm(float x) { return 1.0f / (1.0f + __expf(-x)); }

// ============================ Kernel P: per-group prep ============================
// Front half of the verified monolith + gated GN stats pass -> params to g_params.
__global__ __launch_bounds__(512, 4) void ema_prep(
    const float* __restrict__ x,
    const float* __restrict__ w1, const float* __restrict__ b1,
    const float* __restrict__ w3, const float* __restrict__ b3,
    const float* __restrict__ w5, const float* __restrict__ b5,
    const float* __restrict__ gnw, const float* __restrict__ gnb,
    const float* __restrict__ ew, const float* __restrict__ eb)
{
  __shared__ float s_row[16][64], s_col[16][64];
  __shared__ float s_RS[16][25];
  __shared__ float s_p2[16][16], s_p3[16][16];
  __shared__ __align__(16) float s_sh[16][64];
  __shared__ __align__(16) float s_sw[16][64];
  __shared__ __align__(16) float s_W5[16][28];
  __shared__ float s_w1[256], s_b1[16], s_gnw[16], s_gnb[16], s_b3[16], s_b5[16], s_ecaw[3], s_ecab[1];
  __shared__ float s_m2[16], s_m3[16], s_sm1[16], s_sm2[16], s_sm3[16];
  __shared__ float s_a1[16], s_a2[16], s_a3[16], s_total[16], s_ca[16];
  __shared__ float s_A1[16], s_Cc[16];
  __shared__ float s_scal[2];     // [0]=total constant Ct, [1]=bias_eff

  const int g = blockIdx.x;
  const int t = threadIdx.x;
  const int wv = t >> 6;
  const int ln = t & 63;
  const float* px = x + (size_t)g * CG * HWN;

  // ---------------- Phase 1: row/col sums; wave w owns channels 2w, 2w+1 ----------------
  {
    const int j4 = ln & 15;
    const int rr = ln >> 4;
    #pragma unroll 1
    for (int cc = 0; cc < 2; ++cc) {
      const int c = 2 * wv + cc;
      float rs[16];
      float cp0 = 0.f, cp1 = 0.f, cp2 = 0.f, cp3 = 0.f;
      #pragma unroll
      for (int j = 0; j < 16; ++j) {
        float4 v = *(const float4*)(px + c * HWN + (rr + 4 * j) * 64 + 4 * j4);
        rs[j] = v.x + v.y + v.z + v.w;
        cp0 += v.x; cp1 += v.y; cp2 += v.z; cp3 += v.w;
      }
      #pragma unroll
      for (int j = 0; j < 16; ++j) {
        float r = rs[j];
        r += __shfl_xor(r, 1); r += __shfl_xor(r, 2);
        r += __shfl_xor(r, 4); r += __shfl_xor(r, 8);
        if (j4 == 0) s_row[c][rr + 4 * j] = r;
      }
      cp0 += __shfl_xor(cp0, 16); cp0 += __shfl_xor(cp0, 32);
      cp1 += __shfl_xor(cp1, 16); cp1 += __shfl_xor(cp1, 32);
      cp2 += __shfl_xor(cp2, 16); cp2 += __shfl_xor(cp2, 32);
      cp3 += __shfl_xor(cp3, 16); cp3 += __shfl_xor(cp3, 32);
      if (rr == 0) *(float4*)&s_col[c][4 * j4] = make_float4(cp0, cp1, cp2, cp3);
    }
  }
  if (t < 256) s_w1[t] = w1[t];
  if (t < 16) {
    s_b1[t]  = b1[t];  s_gnw[t] = gnw[t]; s_gnb[t] = gnb[t];
    s_b3[t]  = b3[t];  s_b5[t]  = b5[t];
  }
  if (t < 3)  s_ecaw[t] = ew[t];
  if (t == 0) s_ecab[0] = eb[0];
  __syncthreads();

  if (t < 16) { float s = 0.f; for (int y = 0; y < 64; ++y) s += s_row[t][y]; s_total[t] = s; }
  __syncthreads();

  // ---------------- conv1x1 (+sigmoid), 5x5 region sums ----------------
  #pragma unroll
  for (int m = 0; m < 4; ++m) {
    int idx = t + 512 * m; int o = idx >> 7, pos = idx & 127;
    float acc = s_b1[o];
    const float inv64 = 1.0f / 64.0f;
    #pragma unroll
    for (int i = 0; i < 16; ++i) {
      float v = (pos < 64 ? s_row[i][pos] : s_col[i][pos - 64]) * inv64;
      acc += s_w1[o * 16 + i] * v;
    }
    float sg = sigm(acc);
    if (pos < 64) s_sh[o][pos] = sg; else s_sw[o][pos - 64] = sg;
  }
  if (t < 400) {
    int i = t / 25, kk = t % 25;
    int dy = kk / 5 - 2, dx = kk % 5 - 2;
    int a  = dy > 0 ? dy : 0,   b  = 64 + (dy < 0 ? dy : 0);
    int cl = dx > 0 ? dx : 0,   d  = 64 + (dx < 0 ? dx : 0);
    float S = s_total[i];
    if (a > 0)  S -= s_row[i][0];
    if (a > 1)  S -= s_row[i][1];
    if (b < 64) S -= s_row[i][63];
    if (b < 63) S -= s_row[i][62];
    for (int x0 = 0; x0 < cl; ++x0) {
      float cv = s_col[i][x0];
      if (a > 0)  cv -= px[i * HWN + 0 * 64  + x0];
      if (a > 1)  cv -= px[i * HWN + 1 * 64  + x0];
      if (b < 64) cv -= px[i * HWN + 63 * 64 + x0];
      if (b < 63) cv -= px[i * HWN + 62 * 64 + x0];
      S -= cv;
    }
    for (int x0 = d; x0 < 64; ++x0) {
      float cv = s_col[i][x0];
      if (a > 0)  cv -= px[i * HWN + 0 * 64  + x0];
      if (a > 1)  cv -= px[i * HWN + 1 * 64  + x0];
      if (b < 64) cv -= px[i * HWN + 63 * 64 + x0];
      if (b < 63) cv -= px[i * HWN + 62 * 64 + x0];
      S -= cv;
    }
    s_RS[i][kk] = S;
  }
  __syncthreads();

  // ---------------- mean(x2), mean(x3) ----------------
  if (t < 256) {
    int o = t >> 4, i = t & 15;
    float p2 = 0.f, p3 = 0.f;
    const float* w3b = w3 + (o * 16 + i) * 9;
    const float* w5b = w5 + (o * 16 + i) * 25;
    #pragma unroll
    for (int ky = 0; ky < 3; ++ky)
      #pragma unroll
      for (int kx = 0; kx < 3; ++kx)
        p2 += w3b[ky * 3 + kx] * s_RS[i][(ky + 1) * 5 + (kx + 1)];
    #pragma unroll
    for (int kk = 0; kk < 25; ++kk) p3 += w5b[kk] * s_RS[i][kk];
    s_p2[o][i] = p2; s_p3[o][i] = p3;
  }
  __syncthreads();
  if (t < 16)      { float s = 0.f; for (int i = 0; i < 16; ++i) s += s_p2[t][i];      s_m2[t] = s_b3[t] + s * (1.0f/4096.0f); }
  else if (t < 32) { int o = t - 16; float s = 0.f; for (int i = 0; i < 16; ++i) s += s_p3[o][i]; s_m3[o] = s_b5[o] + s * (1.0f/4096.0f); }
  __syncthreads();

  // ---------------- softmaxes (mean(x1) == gn_b exactly) ----------------
  if (t < 3) {
    const float* m = (t == 0) ? s_gnb : (t == 1) ? s_m2 : s_m3;
    float* dst     = (t == 0) ? s_sm1 : (t == 1) ? s_sm2 : s_sm3;
    float mx = m[0];
    for (int c = 1; c < 16; ++c) mx = fmaxf(mx, m[c]);
    float e[16], ssum = 0.f;
    for (int c = 0; c < 16; ++c) { e[c] = __expf(m[c] - mx); ssum += e[c]; }
    float r = 1.0f / ssum;
    for (int c = 0; c < 16; ++c) dst[c] = e[c] * r;
  }
  __syncthreads();

  // ---------------- ECA (ca) and mixing coefficients ----------------
  if (t < 16) {
    int c = t;
    float casum = 0.f;
    #pragma unroll
    for (int v = 0; v < 3; ++v) {
      const float* m = (v == 0) ? s_gnb : (v == 1) ? s_m2 : s_m3;
      float acc = s_ecab[0] + s_ecaw[1] * m[c];
      if (c > 0)  acc += s_ecaw[0] * m[c - 1];
      if (c < 15) acc += s_ecaw[2] * m[c + 1];
      casum += sigm(acc);
    }
    s_ca[c] = casum;
    s_a1[c] = s_sm2[c] + s_sm3[c];
    s_a2[c] = s_sm1[c] + s_sm3[c];
    s_a3[c] = s_sm1[c] + s_sm2[c];
  }
  __syncthreads();

  // ---------------- effective 5x5 kernel + bias_eff ----------------
  if (t == 0) {
    float s = 0.f;
    for (int o = 0; o < 16; ++o) s += s_a2[o] * s_b3[o] + s_a3[o] * s_b5[o];
    s_scal[1] = s;
  }
  if (t < 448) {
    if (t < 400) {
      int i = t / 25, kk = t % 25, ky = kk / 5, kx = kk % 5;
      float acc = 0.f;
      #pragma unroll
      for (int o = 0; o < 16; ++o) acc += s_a3[o] * w5[((o * 16 + i) * 5 + ky) * 5 + kx];
      if (ky >= 1 && ky <= 3 && kx >= 1 && kx <= 3) {
        #pragma unroll
        for (int o = 0; o < 16; ++o) acc += s_a2[o] * w3[((o * 16 + i) * 3 + (ky - 1)) * 3 + (kx - 1)];
      }
      s_W5[i][kk] = acc;
    } else {
      int q = t - 400; s_W5[q / 3][25 + q % 3] = 0.f;
    }
  }

  // ---------------- gated GN stats: gs = sum(x*sh*sw), gq = sum((.)^2) ----------------
  // (s_sh/s_sw ready since the conv1x1 barrier; s_a1 since the ECA barrier.)
  {
    const int j4 = ln & 15;
    const int rr = ln >> 4;
    #pragma unroll 1
    for (int cc = 0; cc < 2; ++cc) {
      const int c = 2 * wv + cc;
      float gs = 0.f, gq = 0.f;
      const float4 swq = *(const float4*)&s_sw[c][4 * j4];
      #pragma unroll
      for (int j = 0; j < 16; ++j) {
        const int y = rr + 4 * j;
        float4 v = *(const float4*)(px + c * HWN + y * 64 + 4 * j4);
        const float shv = s_sh[c][y];
        float g0 = v.x * shv * swq.x, g1 = v.y * shv * swq.y;
        float g2 = v.z * shv * swq.z, g3 = v.w * shv * swq.w;
        gs += (g0 + g1) + (g2 + g3);
        gq += (g0 * g0 + g1 * g1) + (g2 * g2 + g3 * g3);
      }
      gs += __shfl_xor(gs, 1);  gq += __shfl_xor(gq, 1);
      gs += __shfl_xor(gs, 2);  gq += __shfl_xor(gq, 2);
      gs += __shfl_xor(gs, 4);  gq += __shfl_xor(gq, 4);
      gs += __shfl_xor(gs, 8);  gq += __shfl_xor(gq, 8);
      gs += __shfl_xor(gs, 16); gq += __shfl_xor(gq, 16);
      gs += __shfl_xor(gs, 32); gq += __shfl_xor(gq, 32);
      if (ln == 0) {
        float mu  = gs * (1.0f / 4096.0f);
        float var = gq * (1.0f / 4096.0f) - mu * mu;
        float inv = rsqrtf(var + 1e-5f);
        s_A1[c] = s_a1[c] * s_gnw[c] * inv;
        s_Cc[c] = s_a1[c] * (s_gnb[c] - mu * s_gnw[c] * inv);
      }
    }
  }
  __syncthreads();
  if (t == 0) {
    float s = s_scal[1];
    for (int c = 0; c < 16; ++c) s += s_Cc[c];
    s_scal[0] = s;
  }
  __syncthreads();

  // ---------------- write params ----------------
  float* wp = g_params + (size_t)g * PSTRIDE;
  for (int i = t; i < 1024; i += 512) wp[i]        = s_sh[i >> 6][i & 63];
  for (int i = t; i < 1024; i += 512) wp[1024 + i] = s_sw[i >> 6][i & 63];
  if (t < 448) wp[2048 + t] = s_W5[t / 28][t % 28];
  if (t < 16) { wp[2496 + t] = s_A1[t]; wp[2512 + t] = s_ca[t]; }
  if (t == 0) wp[2528] = s_scal[0];
}

// ============================ Kernel M: conv sweep + output ============================
// One block per (group, 16-row band): grid 2048, 256 threads (4 waves).
// No serial reductions, barriers only for the LDS double buffer.
__global__ __launch_bounds__(256, 6) void ema_main(
    const float* __restrict__ x, float* __restrict__ out)
{
  __shared__ __align__(16) float s_t[2][20][LSTR];   // 20 rows (16 + 2 halo each side)
  __shared__ float m_sh[16][16];                     // sh[c][band rows]
  __shared__ __align__(16) float m_sw[16][64];
  __shared__ __align__(16) float m_W5[16][28];
  __shared__ float m_A1[16], m_ca[16], m_Ct[1];

  const int bid  = blockIdx.x;
  const int g    = bid >> 2;
  const int band = bid & 3;
  const int r0   = band * 16;
  const int t    = threadIdx.x;
  const float* px   = x   + (size_t)g * CG * HWN;
  float*       pout = out + (size_t)g * CG * HWN;
  const float* wp = g_params + (size_t)g * PSTRIDE;

  // load params
  if (t < 256) m_sh[t >> 4][t & 15] = wp[(t >> 4) * 64 + r0 + (t & 15)];
  for (int i = t; i < 1024; i += 256) m_sw[i >> 6][i & 63] = wp[1024 + i];
  for (int i = t; i < 448; i += 256)  m_W5[i / 28][i % 28] = wp[2048 + i];
  if (t < 16) { m_A1[t] = wp[2496 + t]; m_ca[t] = wp[2512 + t]; }
  if (t == 0) m_Ct[0] = wp[2528];
  // zero both tile buffers once; halo cells (cols 0,1,66,67 and OOB rows) stay zero forever
  for (int i = t; i < 2 * 20 * LSTR / 2; i += 256) ((float2*)s_t)[i] = make_float2(0.f, 0.f);
  __syncthreads();

  const int srow = t >> 4, sc4 = t & 15;
  // stage channel c rows r0-2..r0+17 (valid only) into buffer buf
  #define MSTAGE(buf, c) {                                                     \
    { int i = srow, y = r0 - 2 + i;                                            \
      if ((unsigned)y < 64u) {                                                 \
        float4 v = *(const float4*)(px + (size_t)(c) * HWN + y * 64 + 4 * sc4);\
        float* d = &s_t[buf][i][2 + 4 * sc4];                                  \
        *(float2*)d       = make_float2(v.x, v.y);                             \
        *(float2*)(d + 2) = make_float2(v.z, v.w); } }                         \
    if (t < 64) { int i = 16 + srow, y = r0 - 2 + i;                           \
      if ((unsigned)y < 64u) {                                                 \
        float4 v = *(const float4*)(px + (size_t)(c) * HWN + y * 64 + 4 * sc4);\
        float* d = &s_t[buf][i][2 + 4 * sc4];                                  \
        *(float2*)d       = make_float2(v.x, v.y);                             \
        *(float2*)(d + 2) = make_float2(v.z, v.w); } }                         \
  }

  MSTAGE(0, 0);
  __syncthreads();

  const int tx = t & 15, ty = t >> 4;
  const int x0 = 4 * tx;
  float ws0 = 0.f, ws1 = 0.f, ws2 = 0.f, ws3 = 0.f;

  #pragma unroll 1
  for (int c = 0; c < 16; ++c) {
    if (c < 15) MSTAGE((c + 1) & 1, c + 1);
    const int buf = c & 1;
    const float shv = m_sh[c][ty];
    const float sw0 = m_sw[c][x0],     sw1 = m_sw[c][x0 + 1];
    const float sw2 = m_sw[c][x0 + 2], sw3 = m_sw[c][x0 + 3];
    const float a1v = m_A1[c];
    #pragma unroll
    for (int k = 0; k < 5; ++k) {
      const float* rp = &s_t[buf][ty + k][x0];
      float4 A = *(const float4*)rp, B = *(const float4*)(rp + 4);
      const float v0 = A.x, v1 = A.y, v2 = A.z, v3 = A.w;
      const float v4 = B.x, v5 = B.y, v6 = B.z, v7 = B.w;
      const float Wa = m_W5[c][5 * k],     Wb = m_W5[c][5 * k + 1];
      const float Wc = m_W5[c][5 * k + 2], Wd = m_W5[c][5 * k + 3];
      const float We = m_W5[c][5 * k + 4];
      ws0 += Wa * v0 + Wb * v1 + Wc * v2 + Wd * v3 + We * v4;
      ws1 += Wa * v1 + Wb * v2 + Wc * v3 + Wd * v4 + We * v5;
      ws2 += Wa * v2 + Wb * v3 + Wc * v4 + Wd * v5 + We * v6;
      ws3 += Wa * v3 + Wb * v4 + Wc * v5 + Wd * v6 + We * v7;
      if (k == 2) {   // center row: v2..v5 = x at (r0+ty, x0..x0+3)
        ws0 += a1v * (v2 * shv * sw0);
        ws1 += a1v * (v3 * shv * sw1);
        ws2 += a1v * (v4 * shv * sw2);
        ws3 += a1v * (v5 * shv * sw3);
      }
    }
    __syncthreads();
  }

  // epilogue: out = x * ca[c] * sigm(ws + Ct)
  const float Ct = m_Ct[0];
  const float f0 = sigm(ws0 + Ct), f1 = sigm(ws1 + Ct);
  const float f2 = sigm(ws2 + Ct), f3 = sigm(ws3 + Ct);
  const int rowoff = (r0 + ty) * 64 + x0;
  #pragma unroll
  for (int c = 0; c < 16; ++c) {
    const float cav = m_ca[c];
    float4 xv = *(const float4*)(px + c * HWN + rowoff);
    float4 o;
    o.x = xv.x * cav * f0; o.y = xv.y * cav * f1;
    o.z = xv.z * cav * f2; o.w = xv.w * cav * f3;
    *(float4*)(pout + c * HWN + rowoff) = o;
  }
}

extern "C" void kernel_launch(void* const* d_in, const int* in_sizes, int n_in,
                              void* d_out, int out_size, void* d_ws, size_t ws_size,
                              hipStream_t stream) {
  const float* X  = (const float*)d_in[0];
  const float* W1 = (const float*)d_in[1];
  const float* B1 = (const float*)d_in[2];
  const float* W3 = (const float*)d_in[3];
  const float* B3 = (const float*)d_in[4];
  const float* W5 = (const float*)d_in[5];
  const float* B5 = (const float*)d_in[6];
  const float* GW = (const float*)d_in[7];
  const float* GB = (const float*)d_in[8];
  const float* EW = (const float*)d_in[9];
  const float* EB = (const float*)d_in[10];
  float* O = (float*)d_out;
  ema_prep<<<dim3(512), dim3(512), 0, stream>>>(X, W1, B1, W3, B3, W5, B5, GW, GB, EW, EB);
  ema_main<<<dim3(2048), dim3(256), 0, stream>>>(X, O);
}